// Round 1
// baseline (428.321 us; speedup 1.0000x reference)
//
#include <hip/hip_runtime.h>
#include <math.h>

#define H  1024
#define H2 2048
#define H3 3072
#define V  50257
#define L  512

// ---------------- attention scores: s[l] = dot(h0, enc[l]) -------------------
__global__ void k_scores(const float* __restrict__ h0,
                         const float* __restrict__ enc,
                         float* __restrict__ scores) {
    int l = blockIdx.x;          // 512 blocks
    int t = threadIdx.x;         // 256 threads
    const float4* e4 = (const float4*)(enc + (size_t)l * H);
    const float4* h4 = (const float4*)h0;
    float4 a = e4[t];
    float4 b = h4[t];
    float acc = a.x*b.x + a.y*b.y + a.z*b.z + a.w*b.w;
    for (int off = 32; off > 0; off >>= 1) acc += __shfl_down(acc, off, 64);
    __shared__ float s[4];
    int lane = t & 63, wv = t >> 6;
    if (lane == 0) s[wv] = acc;
    __syncthreads();
    if (t == 0) scores[l] = s[0] + s[1] + s[2] + s[3];
}

// ------- softmax over 512 scores (redundant per block) + attn_applied -------
// 32 blocks x 256 threads; block b computes attn_applied columns [32b,32b+32)
__global__ void k_softmax_attn(const float* __restrict__ enc,
                               const float* __restrict__ scores,
                               float* __restrict__ attn_applied,
                               float* __restrict__ d_out) {
    __shared__ float wl[L];
    __shared__ float red[256];
    __shared__ float part[8][32];
    int t = threadIdx.x;
    float s0 = scores[t], s1 = scores[t + 256];
    red[t] = fmaxf(s0, s1);
    __syncthreads();
    for (int off = 128; off > 0; off >>= 1) {
        if (t < off) red[t] = fmaxf(red[t], red[t + off]);
        __syncthreads();
    }
    float gmax = red[0];
    __syncthreads();
    float e0 = expf(s0 - gmax), e1 = expf(s1 - gmax);
    red[t] = e0 + e1;
    __syncthreads();
    for (int off = 128; off > 0; off >>= 1) {
        if (t < off) red[t] += red[t + off];
        __syncthreads();
    }
    float inv = 1.0f / red[0];
    wl[t]       = e0 * inv;
    wl[t + 256] = e1 * inv;
    __syncthreads();
    if (blockIdx.x == 0) {               // attn_weights output
        d_out[V + H + t]       = wl[t];
        d_out[V + H + t + 256] = wl[t + 256];
    }
    // column partial sums: attn_applied[col] = sum_l wl[l]*enc[l][col]
    int c    = t & 31;
    int sIdx = t >> 5;                   // 8 row-stripes of 64
    int col  = blockIdx.x * 32 + c;
    float acc = 0.f;
    for (int l = sIdx * 64; l < sIdx * 64 + 64; ++l)
        acc += wl[l] * enc[(size_t)l * H + col];
    part[sIdx][c] = acc;
    __syncthreads();
    if (sIdx == 0) {
        float sum = 0.f;
        for (int k = 0; k < 8; ++k) sum += part[k][c];
        attn_applied[col] = sum;
    }
}

// --------- x = relu([embedded, attn_applied] @ Wc^T + bc)  (1024 rows) ------
__global__ void __launch_bounds__(256) k_combine(const float* __restrict__ emb_w,
                          const int* __restrict__ tok,
                          const float* __restrict__ attn_applied,
                          const float* __restrict__ Wc,
                          const float* __restrict__ bc,
                          float* __restrict__ x) {
    __shared__ float comb[H2];
    int t = threadIdx.x;                 // 256
    int tk = tok[0];
    ((float4*)comb)[t]       = ((const float4*)(emb_w + (size_t)tk * H))[t];
    ((float4*)comb)[t + 256] = ((const float4*)attn_applied)[t];
    __syncthreads();
    int lane = t & 63, wv = t >> 6;
    int row = blockIdx.x * 4 + wv;       // 256 blocks -> rows 0..1023
    const float4* wr = (const float4*)(Wc + (size_t)row * H2);
    float acc = 0.f;
    for (int j = 0; j < 8; ++j) {
        float4 a = wr[j * 64 + lane];
        float4 b = ((const float4*)comb)[j * 64 + lane];
        acc += a.x*b.x + a.y*b.y + a.z*b.z + a.w*b.w;
    }
    for (int off = 32; off > 0; off >>= 1) acc += __shfl_down(acc, off, 64);
    if (lane == 0) x[row] = fmaxf(acc + bc[row], 0.f);
}

// ------ gi = x @ w_ih^T + b_ih ; gh = h0 @ w_hh^T + b_hh  (6144 row-dots) ---
__global__ void __launch_bounds__(256) k_gates_mm(const float* __restrict__ x,
                           const float* __restrict__ h0,
                           const float* __restrict__ w_ih,
                           const float* __restrict__ w_hh,
                           const float* __restrict__ b_ih,
                           const float* __restrict__ b_hh,
                           float* __restrict__ gi,
                           float* __restrict__ gh) {
    int t = threadIdx.x;
    int lane = t & 63, wv = t >> 6;
    int r = blockIdx.x * 4 + wv;         // 1536 blocks -> 0..6143
    const float *vec, *W, *b; float* o; int row;
    if (r < H3) { vec = x;  W = w_ih; b = b_ih; o = gi; row = r; }
    else        { vec = h0; W = w_hh; b = b_hh; o = gh; row = r - H3; }
    const float4* wr = (const float4*)(W + (size_t)row * H);
    const float4* v4 = (const float4*)vec;
    float acc = 0.f;
    for (int j = 0; j < 4; ++j) {
        float4 a  = wr[j * 64 + lane];
        float4 bb = v4[j * 64 + lane];
        acc += a.x*bb.x + a.y*bb.y + a.z*bb.z + a.w*bb.w;
    }
    for (int off = 32; off > 0; off >>= 1) acc += __shfl_down(acc, off, 64);
    if (lane == 0) o[row] = acc + b[row];
}

// ----------------------------- GRU elementwise ------------------------------
__global__ void k_gru(const float* __restrict__ gi, const float* __restrict__ gh,
                      const float* __restrict__ h0, float* __restrict__ d_out,
                      float* __restrict__ hnew) {
    int i = blockIdx.x * 256 + threadIdx.x;   // grid 4 -> 1024
    float r = 1.f / (1.f + expf(-(gi[i] + gh[i])));
    float z = 1.f / (1.f + expf(-(gi[H + i] + gh[H + i])));
    float n = tanhf(gi[2 * H + i] + r * gh[2 * H + i]);
    float h = (1.f - z) * n + z * h0[i];
    d_out[V + i] = h;
    hnew[i] = h;
}

// ------------- logits[v] = dot(h_new, out_w[v]) + out_b[v] ------------------
__global__ void __launch_bounds__(256) k_logits(const float* __restrict__ hnew,
                         const float* __restrict__ out_w,
                         const float* __restrict__ out_b,
                         float* __restrict__ logits) {
    __shared__ float hs[H];
    int t = threadIdx.x;
    ((float4*)hs)[t] = ((const float4*)hnew)[t];
    __syncthreads();
    int lane = t & 63, wv = t >> 6;
    int row = blockIdx.x * 4 + wv;
    if (row >= V) return;
    const float4* wr = (const float4*)(out_w + (size_t)row * H);
    float acc = 0.f;
    for (int j = 0; j < 4; ++j) {
        float4 a = wr[j * 64 + lane];
        float4 b = ((const float4*)hs)[j * 64 + lane];
        acc += a.x*b.x + a.y*b.y + a.z*b.z + a.w*b.w;
    }
    for (int off = 32; off > 0; off >>= 1) acc += __shfl_down(acc, off, 64);
    if (lane == 0) logits[row] = acc + out_b[row];
}

// ----------------- max + log-sum-exp over V logits (1 block) ----------------
__global__ void k_lse(const float* __restrict__ logits, float* __restrict__ red_out) {
    __shared__ float red[32];
    int t = threadIdx.x;                 // 1024
    int lane = t & 63, wv = t >> 6;      // 16 waves
    float m = -INFINITY;
    for (int i = t; i < V; i += 1024) m = fmaxf(m, logits[i]);
    for (int off = 32; off > 0; off >>= 1) m = fmaxf(m, __shfl_down(m, off, 64));
    if (lane == 0) red[wv] = m;
    __syncthreads();
    if (t == 0) {
        float mm = red[0];
        for (int k = 1; k < 16; ++k) mm = fmaxf(mm, red[k]);
        red[31] = mm;
    }
    __syncthreads();
    float gm = red[31];
    __syncthreads();
    float s = 0.f;
    for (int i = t; i < V; i += 1024) s += expf(logits[i] - gm);
    for (int off = 32; off > 0; off >>= 1) s += __shfl_down(s, off, 64);
    if (lane == 0) red[wv] = s;
    __syncthreads();
    if (t == 0) {
        float ss = 0.f;
        for (int k = 0; k < 16; ++k) ss += red[k];
        red_out[0] = gm;
        red_out[1] = logf(ss);
    }
}

// -------------------------- logp = logits - m - lse -------------------------
__global__ void k_logp(float* __restrict__ d_out, const float* __restrict__ red) {
    int i = blockIdx.x * 256 + threadIdx.x;
    if (i < V) d_out[i] = d_out[i] - red[0] - red[1];
}

extern "C" void kernel_launch(void* const* d_in, const int* in_sizes, int n_in,
                              void* d_out, int out_size, void* d_ws, size_t ws_size,
                              hipStream_t stream) {
    const int*   tok    = (const int*)d_in[0];   // int64 LE, value < 2^31 -> low word OK
    const float* hidden = (const float*)d_in[1];
    const float* enc    = (const float*)d_in[2];
    const float* emb_w  = (const float*)d_in[3];
    const float* Wc     = (const float*)d_in[4];
    const float* bc     = (const float*)d_in[5];
    const float* w_ih   = (const float*)d_in[6];
    const float* w_hh   = (const float*)d_in[7];
    const float* b_ih   = (const float*)d_in[8];
    const float* b_hh   = (const float*)d_in[9];
    const float* out_w  = (const float*)d_in[10];
    const float* out_b  = (const float*)d_in[11];
    float* out = (float*)d_out;
    float* ws  = (float*)d_ws;

    float* scores       = ws;            // 512
    float* attn_applied = ws + 1024;     // 1024
    float* xbuf         = ws + 2048;     // 1024
    float* gi           = ws + 3072;     // 3072
    float* gh           = ws + 6144;     // 3072
    float* hnew         = ws + 9216;     // 1024
    float* red          = ws + 10240;    // 2

    k_scores      <<<512, 256, 0, stream>>>(hidden, enc, scores);
    k_softmax_attn<<<32, 256, 0, stream>>>(enc, scores, attn_applied, out);
    k_combine     <<<256, 256, 0, stream>>>(emb_w, tok, attn_applied, Wc, bc, xbuf);
    k_gates_mm    <<<1536, 256, 0, stream>>>(xbuf, hidden, w_ih, w_hh, b_ih, b_hh, gi, gh);
    k_gru         <<<4, 256, 0, stream>>>(gi, gh, hidden, out, hnew);
    k_logits      <<<(V + 3) / 4, 256, 0, stream>>>(hnew, out_w, out_b, out);
    k_lse         <<<1, 1024, 0, stream>>>(out, red);
    k_logp        <<<(V + 255) / 256, 256, 0, stream>>>(out, red);
}

// Round 2
// 416.996 us; speedup vs baseline: 1.0272x; 1.0272x over previous
//
#include <hip/hip_runtime.h>
#include <math.h>

#define H  1024
#define H2 2048
#define H3 3072
#define V  50257
#define L  512

__device__ __forceinline__ float dot4(float4 a, float4 b) {
    return a.x*b.x + a.y*b.y + a.z*b.z + a.w*b.w;
}
__device__ __forceinline__ float wave_red_sum(float acc) {
    for (int off = 32; off > 0; off >>= 1) acc += __shfl_down(acc, off, 64);
    return acc;
}

// ---- K1: blocks 0..511 attention scores; blocks 512..1279 gh GEMV ----------
// scores[l] = dot(h0, enc[l]);  gh[r] = dot(h0, w_hh[r]) + b_hh[r]
__global__ void __launch_bounds__(256) k_pre(
        const float* __restrict__ h0, const float* __restrict__ enc,
        const float* __restrict__ w_hh, const float* __restrict__ b_hh,
        float* __restrict__ scores, float* __restrict__ gh) {
    __shared__ float s[4];
    int t = threadIdx.x, lane = t & 63, wv = t >> 6;
    if (blockIdx.x < 512) {
        int l = blockIdx.x;
        float4 a = ((const float4*)(enc + (size_t)l * H))[t];
        float4 b = ((const float4*)h0)[t];
        float acc = wave_red_sum(dot4(a, b));
        if (lane == 0) s[wv] = acc;
        __syncthreads();
        if (t == 0) scores[l] = s[0] + s[1] + s[2] + s[3];
    } else {
        int row = (blockIdx.x - 512) * 4 + wv;          // 0..3071
        const float4* wr = (const float4*)(w_hh + (size_t)row * H);
        const float4* h4 = (const float4*)h0;
        float acc = 0.f;
        #pragma unroll
        for (int j = 0; j < 4; ++j) acc += dot4(wr[j * 64 + lane], h4[j * 64 + lane]);
        acc = wave_red_sum(acc);
        if (lane == 0) gh[row] = acc + b_hh[row];
    }
}

// ---- K2: softmax over 512 scores (redundant per block) + attn_applied ------
__global__ void __launch_bounds__(256) k_softmax_attn(
        const float* __restrict__ enc, const float* __restrict__ scores,
        float* __restrict__ attn_applied, float* __restrict__ d_out) {
    __shared__ float wl[L];
    __shared__ float red[256];
    __shared__ float part[8][32];
    int t = threadIdx.x;
    float s0 = scores[t], s1 = scores[t + 256];
    red[t] = fmaxf(s0, s1);
    __syncthreads();
    for (int off = 128; off > 0; off >>= 1) {
        if (t < off) red[t] = fmaxf(red[t], red[t + off]);
        __syncthreads();
    }
    float gmax = red[0];
    __syncthreads();
    float e0 = expf(s0 - gmax), e1 = expf(s1 - gmax);
    red[t] = e0 + e1;
    __syncthreads();
    for (int off = 128; off > 0; off >>= 1) {
        if (t < off) red[t] += red[t + off];
        __syncthreads();
    }
    float inv = 1.0f / red[0];
    wl[t]       = e0 * inv;
    wl[t + 256] = e1 * inv;
    __syncthreads();
    if (blockIdx.x == 0) {
        d_out[V + H + t]       = wl[t];
        d_out[V + H + t + 256] = wl[t + 256];
    }
    int c = t & 31, sIdx = t >> 5;
    int col = blockIdx.x * 32 + c;
    float acc = 0.f;
    for (int l = sIdx * 64; l < sIdx * 64 + 64; ++l)
        acc += wl[l] * enc[(size_t)l * H + col];
    part[sIdx][c] = acc;
    __syncthreads();
    if (sIdx == 0) {
        float sum = 0.f;
        #pragma unroll
        for (int k = 0; k < 8; ++k) sum += part[k][c];
        attn_applied[col] = sum;
    }
}

// ---- K3: x = relu([embedded, attn_applied] @ Wc^T + bc) --------------------
__global__ void __launch_bounds__(256) k_combine(
        const float* __restrict__ emb_w, const int* __restrict__ tok,
        const float* __restrict__ attn_applied, const float* __restrict__ Wc,
        const float* __restrict__ bc, float* __restrict__ x) {
    __shared__ float comb[H2];
    int t = threadIdx.x;
    int tk = tok[0];
    ((float4*)comb)[t]       = ((const float4*)(emb_w + (size_t)tk * H))[t];
    ((float4*)comb)[t + 256] = ((const float4*)attn_applied)[t];
    __syncthreads();
    int lane = t & 63, wv = t >> 6;
    int row = blockIdx.x * 4 + wv;
    const float4* wr = (const float4*)(Wc + (size_t)row * H2);
    float acc = 0.f;
    #pragma unroll
    for (int j = 0; j < 8; ++j) acc += dot4(wr[j * 64 + lane], ((const float4*)comb)[j * 64 + lane]);
    acc = wave_red_sum(acc);
    if (lane == 0) x[row] = fmaxf(acc + bc[row], 0.f);
}

// ---- K4: gi rows (r,z,n per unit) + GRU elementwise, fused -----------------
// wave w of block b owns unit i = b*4+w: computes dot(x, w_ih[k*H+i]) for k=0..2
// then finishes h_new[i] on lane 0.
__global__ void __launch_bounds__(256) k_gi_gru(
        const float* __restrict__ x, const float* __restrict__ h0,
        const float* __restrict__ w_ih, const float* __restrict__ b_ih,
        const float* __restrict__ gh, float* __restrict__ d_out,
        float* __restrict__ hnew) {
    int t = threadIdx.x, lane = t & 63, wv = t >> 6;
    int i = blockIdx.x * 4 + wv;                        // 0..1023
    const float4* xv = (const float4*)x;
    float g[3];
    #pragma unroll
    for (int k = 0; k < 3; ++k) {
        const float4* wr = (const float4*)(w_ih + (size_t)(k * H + i) * H);
        float acc = 0.f;
        #pragma unroll
        for (int j = 0; j < 4; ++j) acc += dot4(wr[j * 64 + lane], xv[j * 64 + lane]);
        g[k] = wave_red_sum(acc);
    }
    if (lane == 0) {
        float gir = g[0] + b_ih[i];
        float giz = g[1] + b_ih[H + i];
        float gin = g[2] + b_ih[2 * H + i];
        float r = 1.f / (1.f + expf(-(gir + gh[i])));
        float z = 1.f / (1.f + expf(-(giz + gh[H + i])));
        float n = tanhf(gin + r * gh[2 * H + i]);
        float h = (1.f - z) * n + z * h0[i];
        d_out[V + i] = h;
        hnew[i] = h;
    }
}

// ---- K5: logits[v] = dot(h_new, out_w[v]) + out_b[v], 2 rows per wave ------
__global__ void __launch_bounds__(256) k_logits(
        const float* __restrict__ hnew, const float* __restrict__ out_w,
        const float* __restrict__ out_b, float* __restrict__ logits) {
    __shared__ float hs[H];
    int t = threadIdx.x;
    ((float4*)hs)[t] = ((const float4*)hnew)[t];
    __syncthreads();
    int lane = t & 63, wv = t >> 6;
    int row0 = (blockIdx.x * 4 + wv) * 2;
    if (row0 >= V) return;
    const float4* hs4 = (const float4*)hs;
    const float4* w0 = (const float4*)(out_w + (size_t)row0 * H);
    float acc0 = 0.f, acc1 = 0.f;
    if (row0 + 1 < V) {
        const float4* w1 = (const float4*)(out_w + (size_t)(row0 + 1) * H);
        #pragma unroll
        for (int j = 0; j < 4; ++j) {
            float4 b = hs4[j * 64 + lane];
            acc0 += dot4(w0[j * 64 + lane], b);
            acc1 += dot4(w1[j * 64 + lane], b);
        }
        for (int off = 32; off > 0; off >>= 1) {
            acc0 += __shfl_down(acc0, off, 64);
            acc1 += __shfl_down(acc1, off, 64);
        }
        if (lane == 0) {
            logits[row0]     = acc0 + out_b[row0];
            logits[row0 + 1] = acc1 + out_b[row0 + 1];
        }
    } else {
        #pragma unroll
        for (int j = 0; j < 4; ++j) acc0 += dot4(w0[j * 64 + lane], hs4[j * 64 + lane]);
        acc0 = wave_red_sum(acc0);
        if (lane == 0) logits[row0] = acc0 + out_b[row0];
    }
}

// ---- K6: per-block (max, sumexp) partials over logits, 64 blocks -----------
__global__ void __launch_bounds__(256) k_lse_part(
        const float* __restrict__ logits, float* __restrict__ pm,
        float* __restrict__ ps) {
    __shared__ float red[4];
    int b = blockIdx.x, t = threadIdx.x, lane = t & 63, wv = t >> 6;
    const int CH = (V + 63) / 64;                       // 786
    int begin = b * CH;
    int end = begin + CH; if (end > V) end = V;
    float v[4]; int cnt = 0;
    for (int i = begin + t; i < end; i += 256) v[cnt++] = logits[i];
    float m = -INFINITY;
    for (int c = 0; c < cnt; ++c) m = fmaxf(m, v[c]);
    for (int off = 32; off > 0; off >>= 1) m = fmaxf(m, __shfl_down(m, off, 64));
    if (lane == 0) red[wv] = m;
    __syncthreads();
    float M = fmaxf(fmaxf(red[0], red[1]), fmaxf(red[2], red[3]));
    __syncthreads();
    float s = 0.f;
    for (int c = 0; c < cnt; ++c) s += expf(v[c] - M);
    s = wave_red_sum(s);
    if (lane == 0) red[wv] = s;
    __syncthreads();
    if (t == 0) {
        pm[b] = M;
        ps[b] = red[0] + red[1] + red[2] + red[3];
    }
}

// ---- K7: combine 64 partials (stable LSE) + write logp in place ------------
__global__ void __launch_bounds__(256) k_logp(
        float* __restrict__ d_out, const float* __restrict__ pm,
        const float* __restrict__ ps) {
    __shared__ float sh[2];
    int t = threadIdx.x;
    if (t < 64) {
        float m = pm[t], s = ps[t];
        float M = m;
        for (int off = 32; off > 0; off >>= 1) M = fmaxf(M, __shfl_down(M, off, 64));
        M = __shfl(M, 0, 64);
        float sc = s * expf(m - M);
        sc = wave_red_sum(sc);
        if (t == 0) { sh[0] = M; sh[1] = logf(sc); }
    }
    __syncthreads();
    float M = sh[0], Ls = sh[1];
    int i = blockIdx.x * 256 + t;
    if (i < V) d_out[i] = d_out[i] - M - Ls;
}

extern "C" void kernel_launch(void* const* d_in, const int* in_sizes, int n_in,
                              void* d_out, int out_size, void* d_ws, size_t ws_size,
                              hipStream_t stream) {
    const int*   tok    = (const int*)d_in[0];
    const float* hidden = (const float*)d_in[1];
    const float* enc    = (const float*)d_in[2];
    const float* emb_w  = (const float*)d_in[3];
    const float* Wc     = (const float*)d_in[4];
    const float* bc     = (const float*)d_in[5];
    const float* w_ih   = (const float*)d_in[6];
    const float* w_hh   = (const float*)d_in[7];
    const float* b_ih   = (const float*)d_in[8];
    const float* b_hh   = (const float*)d_in[9];
    const float* out_w  = (const float*)d_in[10];
    const float* out_b  = (const float*)d_in[11];
    float* out = (float*)d_out;
    float* ws  = (float*)d_ws;

    float* scores       = ws;            // 512
    float* gh           = ws + 1024;     // 3072
    float* attn_applied = ws + 4096;     // 1024
    float* xbuf         = ws + 5120;     // 1024
    float* hnew         = ws + 6144;     // 1024
    float* pm           = ws + 7168;     // 64
    float* psum         = ws + 7232;     // 64

    k_pre         <<<1280, 256, 0, stream>>>(hidden, enc, w_hh, b_hh, scores, gh);
    k_softmax_attn<<<32,   256, 0, stream>>>(enc, scores, attn_applied, out);
    k_combine     <<<256,  256, 0, stream>>>(emb_w, tok, attn_applied, Wc, bc, xbuf);
    k_gi_gru      <<<256,  256, 0, stream>>>(xbuf, hidden, w_ih, b_ih, gh, out, hnew);
    k_logits      <<<(V + 7) / 8, 256, 0, stream>>>(hnew, out_w, out_b, out);
    k_lse_part    <<<64,   256, 0, stream>>>(out, pm, psum);
    k_logp        <<<(V + 255) / 256, 256, 0, stream>>>(out, pm, psum);
}